// Round 5
// baseline (1471.246 us; speedup 1.0000x reference)
//
#include <hip/hip_runtime.h>
#include <hip/hip_bf16.h>
#include <math.h>

#define S 512
#define B 8
#define H 768
#define NH 12
#define DH 64
#define DV 192
#define II 2304
#define NL 4
#define SCALE 0.07216878364870322f
#define EPS 1e-7f

typedef __attribute__((ext_vector_type(8))) short short8;
typedef __attribute__((ext_vector_type(4))) float f32x4;

__device__ __forceinline__ float b2f(ushort u){
  union { float f; unsigned int u; } v; v.u = ((unsigned int)u) << 16; return v.f;
}
__device__ __forceinline__ ushort f2b(float f){
  union { float f; unsigned int u; } v; v.f = f;
  unsigned int u = v.u;
  return (ushort)((u + 0x7fffu + ((u >> 16) & 1u)) >> 16);
}
__device__ __forceinline__ float gelu_f(float x){
  return 0.5f * x * (1.0f + erff(x * 0.70710678118654752f));
}
// async global(16B/lane) -> LDS (wave-uniform base + lane*16)
__device__ __forceinline__ void async_copy16(const ushort* g, ushort* l){
  __builtin_amdgcn_global_load_lds(
      (const __attribute__((address_space(1))) void*)g,
      (__attribute__((address_space(3))) void*)l, 16, 0, 0);
}

// ---- block-wide sum of two floats across 256 threads (4 waves) ----
__device__ __forceinline__ void block_sum2(float& s, float& s2, float* red, int t){
  #pragma unroll
  for(int off=32; off>=1; off>>=1){ s += __shfl_xor(s, off); s2 += __shfl_xor(s2, off); }
  int w = t >> 6;
  if((t & 63) == 0){ red[w] = s; red[4 + w] = s2; }
  __syncthreads();
  s  = red[0] + red[1] + red[2] + red[3];
  s2 = red[4] + red[5] + red[6] + red[7];
}

// ---- f32 -> bf16 bulk convert (n divisible by 1024) ----
__global__ __launch_bounds__(256)
void f2b_kernel(const float* __restrict__ in, ushort* __restrict__ out){
  int i = (blockIdx.x * 256 + threadIdx.x) * 4;
  float4 v = *(const float4*)(in + i);
  __attribute__((aligned(8))) ushort tmp[4] = { f2b(v.x), f2b(v.y), f2b(v.z), f2b(v.w) };
  *(uint2*)(out + i) = *(const uint2*)tmp;
}

// ---- x = LN(word_emb[ids])  (f32 in, f32 out) ----
__global__ __launch_bounds__(256)
void embed_ln_kernel(const int* __restrict__ ids, const float* __restrict__ wemb,
                     float* __restrict__ x)
{
  __shared__ float red[8];
  const int sb = blockIdx.x, t = threadIdx.x;
  const float* row = wemb + (size_t)ids[sb] * H;
  float v0 = row[t], v1 = row[t+256], v2 = row[t+512];
  float s = v0+v1+v2, s2 = v0*v0+v1*v1+v2*v2;
  block_sum2(s, s2, red, t);
  float mean = s * (1.0f/H);
  float rstd = rsqrtf(s2*(1.0f/H) - mean*mean + EPS);
  float* xo = x + (size_t)sb * H;
  xo[t]     = (v0-mean)*rstd;
  xo[t+256] = (v1-mean)*rstd;
  xo[t+512] = (v2-mean)*rstd;
}

// ---- relb = LN(rel_emb)*w + b  (f32 in, bf16 out) ----
__global__ __launch_bounds__(256)
void rel_ln_kernel(const float* __restrict__ rel_emb, const float* __restrict__ w,
                   const float* __restrict__ bia, ushort* __restrict__ outb)
{
  __shared__ float red[8];
  const int j = blockIdx.x, t = threadIdx.x;
  const float* row = rel_emb + (size_t)j * H;
  float v0=row[t], v1=row[t+256], v2=row[t+512];
  float s=v0+v1+v2, s2=v0*v0+v1*v1+v2*v2;
  block_sum2(s,s2,red,t);
  float mean = s*(1.0f/H);
  float rstd = rsqrtf(s2*(1.0f/H)-mean*mean+EPS);
  ushort* o = outb + (size_t)j*H;
  o[t]     = f2b((v0-mean)*rstd * w[t]     + bia[t]);
  o[t+256] = f2b((v1-mean)*rstd * w[t+256] + bia[t+256]);
  o[t+512] = f2b((v2-mean)*rstd * w[t+512] + bia[t+512]);
}

// ---- h = LN(x)  (bf16 out) ----
__global__ __launch_bounds__(256)
void ln_x_kernel(const float* __restrict__ x, ushort* __restrict__ h)
{
  __shared__ float red[8];
  const int sb = blockIdx.x, t = threadIdx.x;
  const float* row = x + (size_t)sb * H;
  float v0 = row[t], v1 = row[t+256], v2 = row[t+512];
  float s = v0+v1+v2, s2 = v0*v0+v1*v1+v2*v2;
  block_sum2(s, s2, red, t);
  float mean = s * (1.0f/H);
  float rstd = rsqrtf(s2*(1.0f/H) - mean*mean + EPS);
  ushort* o = h + (size_t)sb * H;
  o[t]     = f2b((v0-mean)*rstd);
  o[t+256] = f2b((v1-mean)*rstd);
  o[t+512] = f2b((v2-mean)*rstd);
}

// ---- small GEMM (64x64 tile): used only for pos = relb @ Wqk^T + bqk (M=63) ----
__global__ __launch_bounds__(256)
void gemm_nt64(const ushort* __restrict__ A, const ushort* __restrict__ Bw,
               const float* __restrict__ bias, ushort* __restrict__ Cout,
               int M, int N, int K)
{
  __shared__ ushort As[64][40];
  __shared__ ushort Bs[64][40];
  const int n0 = blockIdx.x * 64, m0 = blockIdx.y * 64;
  const int t = threadIdx.x;
  const int lrow = t >> 2, lk = (t & 3) * 8;
  const int lane = t & 63, w = t >> 6, lr = lane & 15, lq = lane >> 4;
  const int wr = (w >> 1) * 32, wc = (w & 1) * 32;
  f32x4 z = {0.f,0.f,0.f,0.f};
  f32x4 acc[2][2] = {{z,z},{z,z}};
  const int arow = m0 + lrow;
  const ushort* aptr = A  + (size_t)arow * K + lk;
  const ushort* bptr = Bw + (size_t)(n0 + lrow) * K + lk;
  for(int k0 = 0; k0 < K; k0 += 32){
    short8 av = {0,0,0,0,0,0,0,0};
    if(arow < M) av = *(const short8*)(aptr + k0);
    short8 bv = *(const short8*)(bptr + k0);
    __syncthreads();
    *(short8*)&As[lrow][lk] = av;
    *(short8*)&Bs[lrow][lk] = bv;
    __syncthreads();
    short8 a0 = *(const short8*)&As[wr + lr][lq * 8];
    short8 a1 = *(const short8*)&As[wr + 16 + lr][lq * 8];
    short8 b0 = *(const short8*)&Bs[wc + lr][lq * 8];
    short8 b1 = *(const short8*)&Bs[wc + 16 + lr][lq * 8];
    acc[0][0] = __builtin_amdgcn_mfma_f32_16x16x32_bf16(a0, b0, acc[0][0], 0,0,0);
    acc[0][1] = __builtin_amdgcn_mfma_f32_16x16x32_bf16(a0, b1, acc[0][1], 0,0,0);
    acc[1][0] = __builtin_amdgcn_mfma_f32_16x16x32_bf16(a1, b0, acc[1][0], 0,0,0);
    acc[1][1] = __builtin_amdgcn_mfma_f32_16x16x32_bf16(a1, b1, acc[1][1], 0,0,0);
  }
  #pragma unroll
  for(int i=0;i<2;i++){
    #pragma unroll
    for(int j=0;j<2;j++){
      #pragma unroll
      for(int r=0;r<4;r++){
        int m = m0 + wr + i*16 + lq*4 + r;
        int n = n0 + wc + j*16 + lr;
        if(m >= M) continue;
        float v = acc[i][j][r];
        if(bias) v += bias[n];
        Cout[(size_t)m*N + n] = f2b(v);
      }
    }
  }
}

// ---- main GEMM (m97 structure): 128x128 tile, global_load_lds(16B) staging ----
// OUT_MODE: 0 = f32 store, 1 = bf16 store, 2 = f32 accumulate (+=)
template<int OUT_MODE>
__global__ __launch_bounds__(256)
void gemm128(const ushort* __restrict__ A, const ushort* __restrict__ Bw,
             const float* __restrict__ bias, void* __restrict__ Cout,
             int M, int N, int K)
{
  __shared__ ushort As[128*32];
  __shared__ ushort Bs[128*32];
  const int t = threadIdx.x, w = t>>6, lane = t&63, lr = lane&15, lq = lane>>4;
  const int m0 = blockIdx.y*128, n0 = blockIdx.x*128;
  const int wr = (w>>1)*64, wc = (w&1)*64;
  const int srow = (w*2)*16 + (lane>>2);
  const int sk = (lane&3)*8;
  const ushort* aG = A  + (size_t)(m0+srow)*K + sk;
  const ushort* bG = Bw + (size_t)(n0+srow)*K + sk;
  ushort* aL0 = As + (w*2)*512;
  ushort* aL1 = As + (w*2+1)*512;
  ushort* bL0 = Bs + (w*2)*512;
  ushort* bL1 = Bs + (w*2+1)*512;
  f32x4 z = {0.f,0.f,0.f,0.f};
  f32x4 acc[4][4] = {{z,z,z,z},{z,z,z,z},{z,z,z,z},{z,z,z,z}};
  for(int k0 = 0; k0 < K; k0 += 32){
    __syncthreads();
    async_copy16(aG + k0,                 aL0);
    async_copy16(aG + k0 + (size_t)16*K,  aL1);
    async_copy16(bG + k0,                 bL0);
    async_copy16(bG + k0 + (size_t)16*K,  bL1);
    __syncthreads();
    short8 af[4], bf[4];
    #pragma unroll
    for(int i=0;i<4;i++) af[i] = *(const short8*)&As[(wr + i*16 + lr)*32 + lq*8];
    #pragma unroll
    for(int j=0;j<4;j++) bf[j] = *(const short8*)&Bs[(wc + j*16 + lr)*32 + lq*8];
    #pragma unroll
    for(int i=0;i<4;i++)
      #pragma unroll
      for(int j=0;j<4;j++)
        acc[i][j] = __builtin_amdgcn_mfma_f32_16x16x32_bf16(af[i], bf[j], acc[i][j], 0,0,0);
  }
  #pragma unroll
  for(int i=0;i<4;i++){
    #pragma unroll
    for(int j=0;j<4;j++){
      #pragma unroll
      for(int r=0;r<4;r++){
        int m = m0 + wr + i*16 + lq*4 + r;
        int n = n0 + wc + j*16 + lr;
        float v = acc[i][j][r];
        if(bias) v += bias[n];
        if(OUT_MODE == 0)      ((float*) Cout)[(size_t)m*N + n] = v;
        else if(OUT_MODE == 1) ((ushort*)Cout)[(size_t)m*N + n] = f2b(v);
        else                   ((float*) Cout)[(size_t)m*N + n] += v;
      }
    }
  }
}

// ---- fused vg+qk GEMM: Ww = [Wv(4608) ; Wqk(1536)] rows x 768, N=6144 ----
// n<4608 -> vg (bf16, no bias); n>=4608 -> qk (bf16, +bqk[n-4608])
__global__ __launch_bounds__(256)
void gemm_vgqk(const ushort* __restrict__ A, const ushort* __restrict__ Ww,
               const float* __restrict__ bqk, ushort* __restrict__ vg,
               ushort* __restrict__ qk)
{
  const int K = H;
  __shared__ ushort As[128*32];
  __shared__ ushort Bs[128*32];
  const int t = threadIdx.x, w = t>>6, lane = t&63, lr = lane&15, lq = lane>>4;
  const int m0 = blockIdx.y*128, n0 = blockIdx.x*128;
  const int wr = (w>>1)*64, wc = (w&1)*64;
  const int srow = (w*2)*16 + (lane>>2);
  const int sk = (lane&3)*8;
  const ushort* aG = A  + (size_t)(m0+srow)*K + sk;
  const ushort* bG = Ww + (size_t)(n0+srow)*K + sk;
  ushort* aL0 = As + (w*2)*512;
  ushort* aL1 = As + (w*2+1)*512;
  ushort* bL0 = Bs + (w*2)*512;
  ushort* bL1 = Bs + (w*2+1)*512;
  f32x4 z = {0.f,0.f,0.f,0.f};
  f32x4 acc[4][4] = {{z,z,z,z},{z,z,z,z},{z,z,z,z},{z,z,z,z}};
  for(int k0 = 0; k0 < K; k0 += 32){
    __syncthreads();
    async_copy16(aG + k0,                 aL0);
    async_copy16(aG + k0 + (size_t)16*K,  aL1);
    async_copy16(bG + k0,                 bL0);
    async_copy16(bG + k0 + (size_t)16*K,  bL1);
    __syncthreads();
    short8 af[4], bf[4];
    #pragma unroll
    for(int i=0;i<4;i++) af[i] = *(const short8*)&As[(wr + i*16 + lr)*32 + lq*8];
    #pragma unroll
    for(int j=0;j<4;j++) bf[j] = *(const short8*)&Bs[(wc + j*16 + lr)*32 + lq*8];
    #pragma unroll
    for(int i=0;i<4;i++)
      #pragma unroll
      for(int j=0;j<4;j++)
        acc[i][j] = __builtin_amdgcn_mfma_f32_16x16x32_bf16(af[i], bf[j], acc[i][j], 0,0,0);
  }
  const bool is_qk = (n0 >= 2*II);   // 4608-aligned blocks: uniform per block
  #pragma unroll
  for(int i=0;i<4;i++){
    #pragma unroll
    for(int j=0;j<4;j++){
      #pragma unroll
      for(int r=0;r<4;r++){
        int m = m0 + wr + i*16 + lq*4 + r;
        int n = n0 + wc + j*16 + lr;
        float v = acc[i][j][r];
        if(is_qk){
          int nq = n - 2*II;
          qk[(size_t)m*(2*H) + nq] = f2b(v + bqk[nq]);
        } else {
          vg[(size_t)m*(2*II) + n] = f2b(v);
        }
      }
    }
  }
}

// ---- cp/cq transposed via MFMA ----
__global__ __launch_bounds__(256)
void cpq_mfma2_kernel(const ushort* __restrict__ qk, const ushort* __restrict__ posb,
                      ushort* __restrict__ cpT, ushort* __restrict__ cqT)
{
  const int kc = blockIdx.x;
  const int bh = blockIdx.y;
  const int bb = bh / NH, h = bh - bb*NH;
  const int which = blockIdx.z;
  const int t = threadIdx.x, w = t>>6, lane = t&63, lr = lane&15, lq = lane>>4;
  const ushort* ab = posb + (size_t)(w*16 + lr)*1536 + (which ? 0 : 768) + h*64;
  short8 a0 = *(const short8*)(ab + lq*8);
  short8 a1 = *(const short8*)(ab + 32 + lq*8);
  f32x4 z = {0.f,0.f,0.f,0.f};
  f32x4 acc[8] = {z,z,z,z,z,z,z,z};
  #pragma unroll
  for(int nt=0; nt<8; nt++){
    const int k = kc*128 + nt*16 + lr;
    const ushort* bp = qk + ((size_t)k*B + bb)*1536 + (which ? 768 : 0) + h*64;
    short8 b0 = *(const short8*)(bp + lq*8);
    short8 b1 = *(const short8*)(bp + 32 + lq*8);
    acc[nt] = __builtin_amdgcn_mfma_f32_16x16x32_bf16(a0, b0, acc[nt], 0,0,0);
    acc[nt] = __builtin_amdgcn_mfma_f32_16x16x32_bf16(a1, b1, acc[nt], 0,0,0);
  }
  ushort* outp = which ? cqT : cpT;
  #pragma unroll
  for(int nt=0; nt<8; nt++){
    #pragma unroll
    for(int r=0;r<4;r++){
      int j = w*16 + lq*4 + r;
      int k = kc*128 + nt*16 + lr;
      outp[((size_t)bh*64 + j)*512 + k] = f2b(acc[nt][r]);
    }
  }
}

// ---- Vt[b][h][v][s] = value[s][b][h*DV+v]  (bf16) ----
__global__ __launch_bounds__(256)
void vt_kernel(const ushort* __restrict__ vg, ushort* __restrict__ vt)
{
  const int st = blockIdx.x, hh = blockIdx.y, b = blockIdx.z;
  __shared__ ushort tile[32][200];
  const int t = threadIdx.x;
  {
    int sl = t >> 3, v0 = (t & 7) * 24;
    const ushort* src = vg + ((size_t)((st*32 + sl)*B + b))*(2*II) + hh*DV + v0;
    *(short8*)&tile[sl][v0]      = *(const short8*)(src);
    *(short8*)&tile[sl][v0 + 8]  = *(const short8*)(src + 8);
    *(short8*)&tile[sl][v0 + 16] = *(const short8*)(src + 16);
  }
  __syncthreads();
  if(t < DV){
    __attribute__((aligned(16))) ushort tmp[32];
    #pragma unroll
    for(int s2=0;s2<32;s2++) tmp[s2] = tile[s2][t];
    ushort* dst = vt + (((size_t)(b*NH + hh))*DV + t)*S + st*32;
    #pragma unroll
    for(int c=0;c<32;c+=8) *(short8*)(dst + c) = *(const short8*)&tmp[c];
  }
}

// ---- fused attention; grid (bh=96, qt=32) so same-(b,h) blocks share XCD ----
__global__ __launch_bounds__(256)
void attn_kernel(const ushort* __restrict__ qk, const ushort* __restrict__ vt,
                 const ushort* __restrict__ cpT, const ushort* __restrict__ cqT,
                 const int* __restrict__ pidx, ushort* __restrict__ ctx)
{
  const int bh = blockIdx.x, qt = blockIdx.y;
  const int b = bh / NH, hh = bh - b*NH;
  __shared__ ushort Qs[16][72];
  __shared__ ushort Ps[16][520];
  __shared__ float cps[16][65];      // 65: stride 65 dwords != 0 mod 32 -> conflict-free writes
  __shared__ float redm[4][16];
  __shared__ float reds[4][16];
  __shared__ float rowinv[16];
  const int t = threadIdx.x, w = t>>6, lane = t&63, lr = lane&15, lq = lane>>4;

  {
    int r = t >> 4, d0 = (t & 15) * 4;
    const ushort* src = qk + ((size_t)((qt*16 + r)*B + b))*1536 + hh*DH + d0;
    *(uint2*)&Qs[r][d0] = *(const uint2*)src;
  }
  for(int i=t; i<16*64; i+=256){
    int j = i >> 4, r = i & 15;
    cps[r][j] = b2f(cpT[((size_t)bh*64 + j)*512 + qt*16 + r]);
  }
  __syncthreads();

  float sc[8][4];
  const int kbase = w * 128;
  const ushort* cqbase = cqT + (size_t)bh*64*512;
  #pragma unroll
  for(int tile=0; tile<8; tile++){
    const int k0 = kbase + tile*16;
    const ushort* kp = qk + ((size_t)((k0 + lr)*B + b))*1536 + H + hh*DH + lq*8;
    short8 b0 = *(const short8*)kp;
    short8 b1 = *(const short8*)(kp + 32);
    short8 a0 = *(const short8*)&Qs[lr][lq*8];
    short8 a1 = *(const short8*)&Qs[lr][32 + lq*8];
    f32x4 acc = {0.f,0.f,0.f,0.f};
    acc = __builtin_amdgcn_mfma_f32_16x16x32_bf16(a0, b0, acc, 0,0,0);
    acc = __builtin_amdgcn_mfma_f32_16x16x32_bf16(a1, b1, acc, 0,0,0);
    const int kcol = k0 + lr;
    #pragma unroll
    for(int r=0;r<4;r++){
      int ql = lq*4 + r;
      int pi = pidx[(qt*16+ql)*S + kcol];
      sc[tile][r] = (acc[r] + cps[ql][pi]
                     + b2f(cqbase[(size_t)pi*512 + kcol])) * SCALE;
    }
  }

  float gm[4], gs[4];
  #pragma unroll
  for(int r=0;r<4;r++){
    float m = sc[0][r];
    #pragma unroll
    for(int tile=1;tile<8;tile++) m = fmaxf(m, sc[tile][r]);
    #pragma unroll
    for(int off=1; off<16; off<<=1) m = fmaxf(m, __shfl_xor(m, off));
    if(lr==0) redm[w][lq*4+r] = m;
  }
  __syncthreads();
  #pragma unroll
  for(int r=0;r<4;r++){
    int row = lq*4+r;
    gm[r] = fmaxf(fmaxf(redm[0][row],redm[1][row]),fmaxf(redm[2][row],redm[3][row]));
  }
  #pragma unroll
  for(int r=0;r<4;r++){
    float s = 0.f;
    #pragma unroll
    for(int tile=0;tile<8;tile++){ float e = __expf(sc[tile][r]-gm[r]); sc[tile][r]=e; s+=e; }
    #pragma unroll
    for(int off=1; off<16; off<<=1) s += __shfl_xor(s, off);
    if(lr==0) reds[w][lq*4+r] = s;
  }
  __syncthreads();
  #pragma unroll
  for(int r=0;r<4;r++){
    int row = lq*4+r;
    gs[r] = reds[0][row]+reds[1][row]+reds[2][row]+reds[3][row];
    if(w==0 && lr==0) rowinv[row] = 1.0f/gs[r];
  }
  #pragma unroll
  for(int tile=0;tile<8;tile++){
    #pragma unroll
    for(int r=0;r<4;r++) Ps[lq*4+r][kbase + tile*16 + lr] = f2b(sc[tile][r]);
  }
  __syncthreads();

  f32x4 z = {0.f,0.f,0.f,0.f};
  f32x4 acc2[3] = {z,z,z};
  const ushort* vbase = vt + ((size_t)bh)*DV*S;
  for(int kk=0; kk<S; kk+=32){
    short8 a = *(const short8*)&Ps[lr][kk + lq*8];
    #pragma unroll
    for(int ti=0; ti<3; ti++){
      const int v0 = (w*3 + ti)*16;
      short8 bv = *(const short8*)(vbase + (size_t)(v0 + lr)*S + kk + lq*8);
      acc2[ti] = __builtin_amdgcn_mfma_f32_16x16x32_bf16(a, bv, acc2[ti], 0,0,0);
    }
  }
  #pragma unroll
  for(int ti=0; ti<3; ti++){
    const int v0 = (w*3 + ti)*16;
    #pragma unroll
    for(int r=0;r<4;r++){
      int ql = lq*4 + r;
      float val = acc2[ti][r] * rowinv[ql];
      ctx[((size_t)((qt*16+ql)*B + b))*II + hh*DV + v0 + lr] = f2b(val);
    }
  }
}

// ---- ctx2 = LN( (ctx + sigmoid(lskip)*gelu(value)) * gelu(gate) )  (bf16) ----
__global__ __launch_bounds__(256)
void glu_ln_kernel(const ushort* __restrict__ ctx, const ushort* __restrict__ vg,
                   const float* __restrict__ ls, ushort* __restrict__ outb)
{
  __shared__ float red[8];
  const int sb = blockIdx.x, t = threadIdx.x;
  const ushort* crow = ctx + (size_t)sb*II;
  const ushort* vrow = vg + (size_t)sb*2*II;
  float c[9]; float s=0.f, s2=0.f;
  #pragma unroll
  for(int i=0;i<9;i++){
    int idx = t + i*256;
    float cv  = b2f(crow[idx]);
    float val = b2f(vrow[idx]);
    float gt  = b2f(vrow[II + idx]);
    float sk  = 1.0f/(1.0f + __expf(-ls[idx]));
    cv = (cv + sk*gelu_f(val)) * gelu_f(gt);
    c[i]=cv; s+=cv; s2+=cv*cv;
  }
  block_sum2(s,s2,red,t);
  float mean = s*(1.0f/II);
  float rstd = rsqrtf(s2*(1.0f/II)-mean*mean+EPS);
  ushort* o = outb + (size_t)sb*II;
  #pragma unroll
  for(int i=0;i<9;i++) o[t+i*256] = f2b((c[i]-mean)*rstd);
}

// ---- final copy x(f32) -> out(f32) ----
__global__ __launch_bounds__(256)
void copy_kernel(const float* __restrict__ x, float* __restrict__ out){
  int i = (blockIdx.x*256 + threadIdx.x)*4;
  *(float4*)(out + i) = *(const float4*)(x + i);
}

extern "C" void kernel_launch(void* const* d_in, const int* in_sizes, int n_in,
                              void* d_out, int out_size, void* d_ws, size_t ws_size,
                              hipStream_t stream)
{
  (void)in_sizes; (void)n_in; (void)out_size; (void)ws_size;
  const int* ids      = (const int*)d_in[0];
  const int* pidx     = (const int*)d_in[2];
  const float* wemb   = (const float*)d_in[3];
  const float* rele   = (const float*)d_in[4];
  const float* rlw    = (const float*)d_in[5];
  const float* rlb    = (const float*)d_in[6];
  const float* Wv     = (const float*)d_in[7];
  const float* Wqk    = (const float*)d_in[8];
  const float* bqk    = (const float*)d_in[9];
  const float* Wo     = (const float*)d_in[10];
  const float* lskip  = (const float*)d_in[11];

  char* wsb = (char*)d_ws;
  float*  x     = (float*) (wsb + 0);           // 12,582,912 B
  ushort* h     = (ushort*)(wsb + 12582912);    //  6,291,456
  ushort* relb  = (ushort*)(wsb + 18874368);    //     98,304
  ushort* posb  = (ushort*)(wsb + 18972672);    //    196,608 (64 rows x 1536 bf16)
  ushort* vg    = (ushort*)(wsb + 19169280);    // 37,748,736
  ushort* qk    = (ushort*)(wsb + 56918016);    // 12,582,912
  ushort* cpT   = (ushort*)(wsb + 69500928);    //  6,291,456 (bf16 [96][64][512])
  ushort* cqT   = (ushort*)(wsb + 75792384);    //  6,291,456
  ushort* ctx   = (ushort*)(wsb + 82083840);    // 18,874,368
  ushort* vt    = (ushort*)(wsb + 100958208);   // 18,874,368
  ushort* ctxln = vt;                           // alias: disjoint live ranges
  ushort* wvqk  = (ushort*)(wsb + 119832576);   //  9,437,184 ([Wv;Wqk] 6144x768 bf16)
  ushort* wqkb  = wvqk + (size_t)(2*II)*H;      //  (tail 1536x768 = Wqk part)
  ushort* wob   = (ushort*)(wsb + 129269760);   //  3,538,944  -> total ~132.8 MB

  embed_ln_kernel<<<S*B, 256, 0, stream>>>(ids, wemb, x);
  rel_ln_kernel<<<63, 256, 0, stream>>>(rele, rlw, rlb, relb);

  for(int l=0; l<NL; l++){
    const float* Wv_l  = Wv  + (size_t)l * (2*II) * H;
    const float* Wqk_l = Wqk + (size_t)l * (2*H) * H;
    const float* bqk_l = bqk + (size_t)l * (2*H);
    const float* Wo_l  = Wo  + (size_t)l * H * II;
    const float* ls_l  = lskip + (size_t)l * II;

    f2b_kernel<<<(2*II*H)/1024, 256, 0, stream>>>(Wv_l, wvqk);
    f2b_kernel<<<(2*H*H)/1024, 256, 0, stream>>>(Wqk_l, wqkb);
    f2b_kernel<<<(H*II)/1024, 256, 0, stream>>>(Wo_l, wob);

    ln_x_kernel<<<S*B, 256, 0, stream>>>(x, h);
    gemm_vgqk<<<dim3((2*II+2*H)/128, (S*B)/128), 256, 0, stream>>>(h, wvqk, bqk_l, vg, qk);
    gemm_nt64<<<dim3((2*H)/64, 1), 256, 0, stream>>>(relb, wqkb, bqk_l, posb, 63, 2*H, H);
    cpq_mfma2_kernel<<<dim3(S/128, B*NH, 2), 256, 0, stream>>>(qk, posb, cpT, cqT);
    vt_kernel<<<dim3(S/32, NH, B), 256, 0, stream>>>(vg, vt);
    attn_kernel<<<dim3(B*NH, S/16), 256, 0, stream>>>(qk, vt, cpT, cqT, pidx, ctx);
    glu_ln_kernel<<<S*B, 256, 0, stream>>>(ctx, vg, ls_l, ctxln);
    gemm128<2><<<dim3(H/128, (S*B)/128), 256, 0, stream>>>(ctxln, wob, nullptr, x, S*B, H, II);
  }
  copy_kernel<<<(S*B*H)/1024, 256, 0, stream>>>(x, (float*)d_out);
}

// Round 6
// 1338.577 us; speedup vs baseline: 1.0991x; 1.0991x over previous
//
#include <hip/hip_runtime.h>
#include <hip/hip_bf16.h>
#include <math.h>

#define S 512
#define B 8
#define H 768
#define NH 12
#define DH 64
#define DV 192
#define II 2304
#define NL 4
#define SCALE 0.07216878364870322f
#define EPS 1e-7f

#define NW0 (2*II*H)   // Wv elems  3,538,944
#define NW1 (2*H*H)    // Wqk elems 1,179,648
#define NW2 (H*II)     // Wo elems  1,769,472

typedef __attribute__((ext_vector_type(8))) short short8;
typedef __attribute__((ext_vector_type(4))) float f32x4;

__device__ __forceinline__ float b2f(ushort u){
  union { float f; unsigned int u; } v; v.u = ((unsigned int)u) << 16; return v.f;
}
__device__ __forceinline__ ushort f2b(float f){
  union { float f; unsigned int u; } v; v.f = f;
  unsigned int u = v.u;
  return (ushort)((u + 0x7fffu + ((u >> 16) & 1u)) >> 16);
}
__device__ __forceinline__ float gelu_f(float x){
  return 0.5f * x * (1.0f + erff(x * 0.70710678118654752f));
}
// async global(16B/lane) -> LDS (wave-uniform base + lane*16)
__device__ __forceinline__ void async_copy16(const ushort* g, ushort* l){
  __builtin_amdgcn_global_load_lds(
      (const __attribute__((address_space(1))) void*)g,
      (__attribute__((address_space(3))) void*)l, 16, 0, 0);
}

// ---- block-wide sum of two floats across 256 threads (4 waves) ----
__device__ __forceinline__ void block_sum2(float& s, float& s2, float* red, int t){
  #pragma unroll
  for(int off=32; off>=1; off>>=1){ s += __shfl_xor(s, off); s2 += __shfl_xor(s2, off); }
  int w = t >> 6;
  if((t & 63) == 0){ red[w] = s; red[4 + w] = s2; }
  __syncthreads();
  s  = red[0] + red[1] + red[2] + red[3];
  s2 = red[4] + red[5] + red[6] + red[7];
}

// ---- fused f32->bf16 convert of Wv|Wqk|Wo into one contiguous bf16 buffer ----
__global__ __launch_bounds__(256)
void f2b3_kernel(const float* __restrict__ in0, const float* __restrict__ in1,
                 const float* __restrict__ in2, ushort* __restrict__ out){
  int i = (blockIdx.x * 256 + threadIdx.x) * 4;
  const float* src; int off;
  if(i < NW0){ src = in0; off = i; }
  else if(i < NW0+NW1){ src = in1; off = i - NW0; }
  else { src = in2; off = i - NW0 - NW1; }
  float4 v = *(const float4*)(src + off);
  __attribute__((aligned(8))) ushort tmp[4] = { f2b(v.x), f2b(v.y), f2b(v.z), f2b(v.w) };
  *(uint2*)(out + i) = *(const uint2*)tmp;
}

// ---- x = LN(word_emb[ids])  (f32 in, f32 out) ----
__global__ __launch_bounds__(256)
void embed_ln_kernel(const int* __restrict__ ids, const float* __restrict__ wemb,
                     float* __restrict__ x)
{
  __shared__ float red[8];
  const int sb = blockIdx.x, t = threadIdx.x;
  const float* row = wemb + (size_t)ids[sb] * H;
  float v0 = row[t], v1 = row[t+256], v2 = row[t+512];
  float s = v0+v1+v2, s2 = v0*v0+v1*v1+v2*v2;
  block_sum2(s, s2, red, t);
  float mean = s * (1.0f/H);
  float rstd = rsqrtf(s2*(1.0f/H) - mean*mean + EPS);
  float* xo = x + (size_t)sb * H;
  xo[t]     = (v0-mean)*rstd;
  xo[t+256] = (v1-mean)*rstd;
  xo[t+512] = (v2-mean)*rstd;
}

// ---- relb = LN(rel_emb)*w + b  (f32 in, bf16 out) ----
__global__ __launch_bounds__(256)
void rel_ln_kernel(const float* __restrict__ rel_emb, const float* __restrict__ w,
                   const float* __restrict__ bia, ushort* __restrict__ outb)
{
  __shared__ float red[8];
  const int j = blockIdx.x, t = threadIdx.x;
  const float* row = rel_emb + (size_t)j * H;
  float v0=row[t], v1=row[t+256], v2=row[t+512];
  float s=v0+v1+v2, s2=v0*v0+v1*v1+v2*v2;
  block_sum2(s,s2,red,t);
  float mean = s*(1.0f/H);
  float rstd = rsqrtf(s2*(1.0f/H)-mean*mean+EPS);
  ushort* o = outb + (size_t)j*H;
  o[t]     = f2b((v0-mean)*rstd * w[t]     + bia[t]);
  o[t+256] = f2b((v1-mean)*rstd * w[t+256] + bia[t+256]);
  o[t+512] = f2b((v2-mean)*rstd * w[t+512] + bia[t+512]);
}

// ---- h = LN(x)  (bf16 out) ----
__global__ __launch_bounds__(256)
void ln_x_kernel(const float* __restrict__ x, ushort* __restrict__ h)
{
  __shared__ float red[8];
  const int sb = blockIdx.x, t = threadIdx.x;
  const float* row = x + (size_t)sb * H;
  float v0 = row[t], v1 = row[t+256], v2 = row[t+512];
  float s = v0+v1+v2, s2 = v0*v0+v1*v1+v2*v2;
  block_sum2(s, s2, red, t);
  float mean = s * (1.0f/H);
  float rstd = rsqrtf(s2*(1.0f/H) - mean*mean + EPS);
  ushort* o = h + (size_t)sb * H;
  o[t]     = f2b((v0-mean)*rstd);
  o[t+256] = f2b((v1-mean)*rstd);
  o[t+512] = f2b((v2-mean)*rstd);
}

// ---- small GEMM (64x64 tile): used only for pos = relb @ Wqk^T + bqk (M=63) ----
__global__ __launch_bounds__(256)
void gemm_nt64(const ushort* __restrict__ A, const ushort* __restrict__ Bw,
               const float* __restrict__ bias, ushort* __restrict__ Cout,
               int M, int N, int K)
{
  __shared__ ushort As[64][40];
  __shared__ ushort Bs[64][40];
  const int n0 = blockIdx.x * 64, m0 = blockIdx.y * 64;
  const int t = threadIdx.x;
  const int lrow = t >> 2, lk = (t & 3) * 8;
  const int lane = t & 63, w = t >> 6, lr = lane & 15, lq = lane >> 4;
  const int wr = (w >> 1) * 32, wc = (w & 1) * 32;
  f32x4 z = {0.f,0.f,0.f,0.f};
  f32x4 acc[2][2] = {{z,z},{z,z}};
  const int arow = m0 + lrow;
  const ushort* aptr = A  + (size_t)arow * K + lk;
  const ushort* bptr = Bw + (size_t)(n0 + lrow) * K + lk;
  for(int k0 = 0; k0 < K; k0 += 32){
    short8 av = {0,0,0,0,0,0,0,0};
    if(arow < M) av = *(const short8*)(aptr + k0);
    short8 bv = *(const short8*)(bptr + k0);
    __syncthreads();
    *(short8*)&As[lrow][lk] = av;
    *(short8*)&Bs[lrow][lk] = bv;
    __syncthreads();
    short8 a0 = *(const short8*)&As[wr + lr][lq * 8];
    short8 a1 = *(const short8*)&As[wr + 16 + lr][lq * 8];
    short8 b0 = *(const short8*)&Bs[wc + lr][lq * 8];
    short8 b1 = *(const short8*)&Bs[wc + 16 + lr][lq * 8];
    acc[0][0] = __builtin_amdgcn_mfma_f32_16x16x32_bf16(a0, b0, acc[0][0], 0,0,0);
    acc[0][1] = __builtin_amdgcn_mfma_f32_16x16x32_bf16(a0, b1, acc[0][1], 0,0,0);
    acc[1][0] = __builtin_amdgcn_mfma_f32_16x16x32_bf16(a1, b0, acc[1][0], 0,0,0);
    acc[1][1] = __builtin_amdgcn_mfma_f32_16x16x32_bf16(a1, b1, acc[1][1], 0,0,0);
  }
  #pragma unroll
  for(int i=0;i<2;i++){
    #pragma unroll
    for(int j=0;j<2;j++){
      #pragma unroll
      for(int r=0;r<4;r++){
        int m = m0 + wr + i*16 + lq*4 + r;
        int n = n0 + wc + j*16 + lr;
        if(m >= M) continue;
        float v = acc[i][j][r];
        if(bias) v += bias[n];
        Cout[(size_t)m*N + n] = f2b(v);
      }
    }
  }
}

// ---- main GEMM (m97 structure): 128x128 tile, global_load_lds(16B) staging ----
// OUT_MODE: 0 = f32 store, 1 = bf16 store, 2 = f32 accumulate (+=)
template<int OUT_MODE>
__global__ __launch_bounds__(256)
void gemm128(const ushort* __restrict__ A, const ushort* __restrict__ Bw,
             const float* __restrict__ bias, void* __restrict__ Cout,
             int M, int N, int K)
{
  __shared__ ushort As[128*32];
  __shared__ ushort Bs[128*32];
  const int t = threadIdx.x, w = t>>6, lane = t&63, lr = lane&15, lq = lane>>4;
  const int m0 = blockIdx.y*128, n0 = blockIdx.x*128;
  const int wr = (w>>1)*64, wc = (w&1)*64;
  const int srow = (w*2)*16 + (lane>>2);
  const int sk = (lane&3)*8;
  const ushort* aG = A  + (size_t)(m0+srow)*K + sk;
  const ushort* bG = Bw + (size_t)(n0+srow)*K + sk;
  ushort* aL0 = As + (w*2)*512;
  ushort* aL1 = As + (w*2+1)*512;
  ushort* bL0 = Bs + (w*2)*512;
  ushort* bL1 = Bs + (w*2+1)*512;
  f32x4 z = {0.f,0.f,0.f,0.f};
  f32x4 acc[4][4] = {{z,z,z,z},{z,z,z,z},{z,z,z,z},{z,z,z,z}};
  for(int k0 = 0; k0 < K; k0 += 32){
    __syncthreads();
    async_copy16(aG + k0,                 aL0);
    async_copy16(aG + k0 + (size_t)16*K,  aL1);
    async_copy16(bG + k0,                 bL0);
    async_copy16(bG + k0 + (size_t)16*K,  bL1);
    __syncthreads();
    short8 af[4], bf[4];
    #pragma unroll
    for(int i=0;i<4;i++) af[i] = *(const short8*)&As[(wr + i*16 + lr)*32 + lq*8];
    #pragma unroll
    for(int j=0;j<4;j++) bf[j] = *(const short8*)&Bs[(wc + j*16 + lr)*32 + lq*8];
    #pragma unroll
    for(int i=0;i<4;i++)
      #pragma unroll
      for(int j=0;j<4;j++)
        acc[i][j] = __builtin_amdgcn_mfma_f32_16x16x32_bf16(af[i], bf[j], acc[i][j], 0,0,0);
  }
  #pragma unroll
  for(int i=0;i<4;i++){
    #pragma unroll
    for(int j=0;j<4;j++){
      #pragma unroll
      for(int r=0;r<4;r++){
        int m = m0 + wr + i*16 + lq*4 + r;
        int n = n0 + wc + j*16 + lr;
        float v = acc[i][j][r];
        if(bias) v += bias[n];
        if(OUT_MODE == 0)      ((float*) Cout)[(size_t)m*N + n] = v;
        else if(OUT_MODE == 1) ((ushort*)Cout)[(size_t)m*N + n] = f2b(v);
        else                   ((float*) Cout)[(size_t)m*N + n] += v;
      }
    }
  }
}

// ---- fused vg+qk GEMM: Ww = [Wv(4608) ; Wqk(1536)] rows x 768, N=6144 ----
__global__ __launch_bounds__(256)
void gemm_vgqk(const ushort* __restrict__ A, const ushort* __restrict__ Ww,
               const float* __restrict__ bqk, ushort* __restrict__ vg,
               ushort* __restrict__ qk)
{
  const int K = H;
  __shared__ ushort As[128*32];
  __shared__ ushort Bs[128*32];
  const int t = threadIdx.x, w = t>>6, lane = t&63, lr = lane&15, lq = lane>>4;
  const int m0 = blockIdx.y*128, n0 = blockIdx.x*128;
  const int wr = (w>>1)*64, wc = (w&1)*64;
  const int srow = (w*2)*16 + (lane>>2);
  const int sk = (lane&3)*8;
  const ushort* aG = A  + (size_t)(m0+srow)*K + sk;
  const ushort* bG = Ww + (size_t)(n0+srow)*K + sk;
  ushort* aL0 = As + (w*2)*512;
  ushort* aL1 = As + (w*2+1)*512;
  ushort* bL0 = Bs + (w*2)*512;
  ushort* bL1 = Bs + (w*2+1)*512;
  f32x4 z = {0.f,0.f,0.f,0.f};
  f32x4 acc[4][4] = {{z,z,z,z},{z,z,z,z},{z,z,z,z},{z,z,z,z}};
  for(int k0 = 0; k0 < K; k0 += 32){
    __syncthreads();
    async_copy16(aG + k0,                 aL0);
    async_copy16(aG + k0 + (size_t)16*K,  aL1);
    async_copy16(bG + k0,                 bL0);
    async_copy16(bG + k0 + (size_t)16*K,  bL1);
    __syncthreads();
    short8 af[4], bf[4];
    #pragma unroll
    for(int i=0;i<4;i++) af[i] = *(const short8*)&As[(wr + i*16 + lr)*32 + lq*8];
    #pragma unroll
    for(int j=0;j<4;j++) bf[j] = *(const short8*)&Bs[(wc + j*16 + lr)*32 + lq*8];
    #pragma unroll
    for(int i=0;i<4;i++)
      #pragma unroll
      for(int j=0;j<4;j++)
        acc[i][j] = __builtin_amdgcn_mfma_f32_16x16x32_bf16(af[i], bf[j], acc[i][j], 0,0,0);
  }
  const bool is_qk = (n0 >= 2*II);
  #pragma unroll
  for(int i=0;i<4;i++){
    #pragma unroll
    for(int j=0;j<4;j++){
      #pragma unroll
      for(int r=0;r<4;r++){
        int m = m0 + wr + i*16 + lq*4 + r;
        int n = n0 + wc + j*16 + lr;
        float v = acc[i][j][r];
        if(is_qk){
          int nq = n - 2*II;
          qk[(size_t)m*(2*H) + nq] = f2b(v + bqk[nq]);
        } else {
          vg[(size_t)m*(2*II) + n] = f2b(v);
        }
      }
    }
  }
}

// ---- cp/cq transposed via MFMA ----
__global__ __launch_bounds__(256)
void cpq_mfma2_kernel(const ushort* __restrict__ qk, const ushort* __restrict__ posb,
                      ushort* __restrict__ cpT, ushort* __restrict__ cqT)
{
  const int kc = blockIdx.x;
  const int bh = blockIdx.y;
  const int bb = bh / NH, h = bh - bb*NH;
  const int which = blockIdx.z;
  const int t = threadIdx.x, w = t>>6, lane = t&63, lr = lane&15, lq = lane>>4;
  const ushort* ab = posb + (size_t)(w*16 + lr)*1536 + (which ? 0 : 768) + h*64;
  short8 a0 = *(const short8*)(ab + lq*8);
  short8 a1 = *(const short8*)(ab + 32 + lq*8);
  f32x4 z = {0.f,0.f,0.f,0.f};
  f32x4 acc[8] = {z,z,z,z,z,z,z,z};
  #pragma unroll
  for(int nt=0; nt<8; nt++){
    const int k = kc*128 + nt*16 + lr;
    const ushort* bp = qk + ((size_t)k*B + bb)*1536 + (which ? 768 : 0) + h*64;
    short8 b0 = *(const short8*)(bp + lq*8);
    short8 b1 = *(const short8*)(bp + 32 + lq*8);
    acc[nt] = __builtin_amdgcn_mfma_f32_16x16x32_bf16(a0, b0, acc[nt], 0,0,0);
    acc[nt] = __builtin_amdgcn_mfma_f32_16x16x32_bf16(a1, b1, acc[nt], 0,0,0);
  }
  ushort* outp = which ? cqT : cpT;
  #pragma unroll
  for(int nt=0; nt<8; nt++){
    #pragma unroll
    for(int r=0;r<4;r++){
      int j = w*16 + lq*4 + r;
      int k = kc*128 + nt*16 + lr;
      outp[((size_t)bh*64 + j)*512 + k] = f2b(acc[nt][r]);
    }
  }
}

// ---- Vt[b][h][v][s] = value[s][b][h*DV+v]  (bf16) ----
__global__ __launch_bounds__(256)
void vt_kernel(const ushort* __restrict__ vg, ushort* __restrict__ vt)
{
  const int st = blockIdx.x, hh = blockIdx.y, b = blockIdx.z;
  __shared__ ushort tile[32][200];
  const int t = threadIdx.x;
  {
    int sl = t >> 3, v0 = (t & 7) * 24;
    const ushort* src = vg + ((size_t)((st*32 + sl)*B + b))*(2*II) + hh*DV + v0;
    *(short8*)&tile[sl][v0]      = *(const short8*)(src);
    *(short8*)&tile[sl][v0 + 8]  = *(const short8*)(src + 8);
    *(short8*)&tile[sl][v0 + 16] = *(const short8*)(src + 16);
  }
  __syncthreads();
  if(t < DV){
    __attribute__((aligned(16))) ushort tmp[32];
    #pragma unroll
    for(int s2=0;s2<32;s2++) tmp[s2] = tile[s2][t];
    ushort* dst = vt + (((size_t)(b*NH + hh))*DV + t)*S + st*32;
    #pragma unroll
    for(int c=0;c<32;c+=8) *(short8*)(dst + c) = *(const short8*)&tmp[c];
  }
}

// ---- fused attention, 32 q-rows per block; grid (bh=96, qt=16) ----
__global__ __launch_bounds__(256)
void attn_kernel(const ushort* __restrict__ qk, const ushort* __restrict__ vt,
                 const ushort* __restrict__ cpT, const ushort* __restrict__ cqT,
                 const int* __restrict__ pidx, ushort* __restrict__ ctx)
{
  const int bh = blockIdx.x, qt = blockIdx.y;
  const int b = bh / NH, hh = bh - b*NH;
  __shared__ ushort Qs[32][72];
  __shared__ ushort Ps[32][520];
  __shared__ float cps[32][65];
  __shared__ float redm[4][32];
  __shared__ float reds[4][32];
  __shared__ float rowinv[32];
  const int t = threadIdx.x, w = t>>6, lane = t&63, lr = lane&15, lq = lane>>4;

  // stage Q (32 rows x 64 d)
  for(int i=t; i<512; i+=256){
    int r = i >> 4, d0 = (i & 15) * 4;
    const ushort* src = qk + ((size_t)((qt*32 + r)*B + b))*1536 + hh*DH + d0;
    *(uint2*)&Qs[r][d0] = *(const uint2*)src;
  }
  // stage cp rows (coalesced from transposed layout)
  for(int i=t; i<32*64; i+=256){
    int j = i >> 5, r = i & 31;
    cps[r][j] = b2f(cpT[((size_t)bh*64 + j)*512 + qt*32 + r]);
  }
  __syncthreads();

  // tile-invariant A fragments (2 q-subtiles x 2 k-halves)
  short8 a00 = *(const short8*)&Qs[lr][lq*8];
  short8 a01 = *(const short8*)&Qs[lr][32 + lq*8];
  short8 a10 = *(const short8*)&Qs[16 + lr][lq*8];
  short8 a11 = *(const short8*)&Qs[16 + lr][32 + lq*8];

  float sc[8][8];
  const int kbase = w * 128;
  const ushort* cqbase = cqT + (size_t)bh*64*512;
  f32x4 z4 = {0.f,0.f,0.f,0.f};
  #pragma unroll
  for(int tile=0; tile<8; tile++){
    const int k0 = kbase + tile*16;
    const ushort* kp = qk + ((size_t)((k0 + lr)*B + b))*1536 + H + hh*DH + lq*8;
    short8 b0 = *(const short8*)kp;
    short8 b1 = *(const short8*)(kp + 32);
    f32x4 acc[2] = {z4, z4};
    acc[0] = __builtin_amdgcn_mfma_f32_16x16x32_bf16(a00, b0, acc[0], 0,0,0);
    acc[0] = __builtin_amdgcn_mfma_f32_16x16x32_bf16(a01, b1, acc[0], 0,0,0);
    acc[1] = __builtin_amdgcn_mfma_f32_16x16x32_bf16(a10, b0, acc[1], 0,0,0);
    acc[1] = __builtin_amdgcn_mfma_f32_16x16x32_bf16(a11, b1, acc[1], 0,0,0);
    const int kcol = k0 + lr;
    #pragma unroll
    for(int qs=0;qs<2;qs++){
      #pragma unroll
      for(int r=0;r<4;r++){
        int ql = qs*16 + lq*4 + r;
        int pi = pidx[(qt*32+ql)*S + kcol];
        sc[tile][qs*4+r] = (acc[qs][r] + cps[ql][pi]
                       + b2f(cqbase[(size_t)pi*512 + kcol])) * SCALE;
      }
    }
  }

  // softmax over k=512; row ql(j) = (j>>2)*16 + lq*4 + (j&3)
  float gm[8];
  #pragma unroll
  for(int j=0;j<8;j++){
    float m = sc[0][j];
    #pragma unroll
    for(int tile=1;tile<8;tile++) m = fmaxf(m, sc[tile][j]);
    #pragma unroll
    for(int off=1; off<16; off<<=1) m = fmaxf(m, __shfl_xor(m, off));
    if(lr==0) redm[w][(j>>2)*16 + lq*4 + (j&3)] = m;
  }
  __syncthreads();
  #pragma unroll
  for(int j=0;j<8;j++){
    int ql = (j>>2)*16 + lq*4 + (j&3);
    gm[j] = fmaxf(fmaxf(redm[0][ql],redm[1][ql]),fmaxf(redm[2][ql],redm[3][ql]));
  }
  #pragma unroll
  for(int j=0;j<8;j++){
    float s = 0.f;
    #pragma unroll
    for(int tile=0;tile<8;tile++){ float e = __expf(sc[tile][j]-gm[j]); sc[tile][j]=e; s+=e; }
    #pragma unroll
    for(int off=1; off<16; off<<=1) s += __shfl_xor(s, off);
    if(lr==0) reds[w][(j>>2)*16 + lq*4 + (j&3)] = s;
  }
  __syncthreads();
  #pragma unroll
  for(int j=0;j<8;j++){
    int ql = (j>>2)*16 + lq*4 + (j&3);
    float g = reds[0][ql]+reds[1][ql]+reds[2][ql]+reds[3][ql];
    if(w==0 && lr==0) rowinv[ql] = 1.0f/g;
  }
  #pragma unroll
  for(int tile=0;tile<8;tile++){
    #pragma unroll
    for(int j=0;j<8;j++){
      int ql = (j>>2)*16 + lq*4 + (j&3);
      Ps[ql][kbase + tile*16 + lr] = f2b(sc[tile][j]);
    }
  }
  __syncthreads();

  // PV: each wave covers 48 v, reused across 2 q-subtiles
  f32x4 acc2[2][3] = {{z4,z4,z4},{z4,z4,z4}};
  const ushort* vbase = vt + ((size_t)bh)*DV*S;
  #pragma unroll 4
  for(int kk=0; kk<S; kk+=32){
    short8 p0 = *(const short8*)&Ps[lr][kk + lq*8];
    short8 p1 = *(const short8*)&Ps[16 + lr][kk + lq*8];
    #pragma unroll
    for(int ti=0; ti<3; ti++){
      const int v0 = (w*3 + ti)*16;
      short8 bv = *(const short8*)(vbase + (size_t)(v0 + lr)*S + kk + lq*8);
      acc2[0][ti] = __builtin_amdgcn_mfma_f32_16x16x32_bf16(p0, bv, acc2[0][ti], 0,0,0);
      acc2[1][ti] = __builtin_amdgcn_mfma_f32_16x16x32_bf16(p1, bv, acc2[1][ti], 0,0,0);
    }
  }
  #pragma unroll
  for(int qs=0;qs<2;qs++){
    #pragma unroll
    for(int ti=0; ti<3; ti++){
      const int v0 = (w*3 + ti)*16;
      #pragma unroll
      for(int r=0;r<4;r++){
        int ql = qs*16 + lq*4 + r;
        float val = acc2[qs][ti][r] * rowinv[ql];
        ctx[((size_t)((qt*32+ql)*B + b))*II + hh*DV + v0 + lr] = f2b(val);
      }
    }
  }
}

// ---- ctx2 = LN( (ctx + sigmoid(lskip)*gelu(value)) * gelu(gate) )  (bf16) ----
__global__ __launch_bounds__(256)
void glu_ln_kernel(const ushort* __restrict__ ctx, const ushort* __restrict__ vg,
                   const float* __restrict__ ls, ushort* __restrict__ outb)
{
  __shared__ float red[8];
  const int sb = blockIdx.x, t = threadIdx.x;
  const ushort* crow = ctx + (size_t)sb*II;
  const ushort* vrow = vg + (size_t)sb*2*II;
  float c[9]; float s=0.f, s2=0.f;
  #pragma unroll
  for(int i=0;i<9;i++){
    int idx = t + i*256;
    float cv  = b2f(crow[idx]);
    float val = b2f(vrow[idx]);
    float gt  = b2f(vrow[II + idx]);
    float sk  = 1.0f/(1.0f + __expf(-ls[idx]));
    cv = (cv + sk*gelu_f(val)) * gelu_f(gt);
    c[i]=cv; s+=cv; s2+=cv*cv;
  }
  block_sum2(s,s2,red,t);
  float mean = s*(1.0f/II);
  float rstd = rsqrtf(s2*(1.0f/II)-mean*mean+EPS);
  ushort* o = outb + (size_t)sb*II;
  #pragma unroll
  for(int i=0;i<9;i++) o[t+i*256] = f2b((c[i]-mean)*rstd);
}

// ---- final copy x(f32) -> out(f32) ----
__global__ __launch_bounds__(256)
void copy_kernel(const float* __restrict__ x, float* __restrict__ out){
  int i = (blockIdx.x*256 + threadIdx.x)*4;
  *(float4*)(out + i) = *(const float4*)(x + i);
}

extern "C" void kernel_launch(void* const* d_in, const int* in_sizes, int n_in,
                              void* d_out, int out_size, void* d_ws, size_t ws_size,
                              hipStream_t stream)
{
  (void)in_sizes; (void)n_in; (void)out_size; (void)ws_size;
  const int* ids      = (const int*)d_in[0];
  const int* pidx     = (const int*)d_in[2];
  const float* wemb   = (const float*)d_in[3];
  const float* rele   = (const float*)d_in[4];
  const float* rlw    = (const float*)d_in[5];
  const float* rlb    = (const float*)d_in[6];
  const float* Wv     = (const float*)d_in[7];
  const float* Wqk    = (const float*)d_in[8];
  const float* bqk    = (const float*)d_in[9];
  const float* Wo     = (const float*)d_in[10];
  const float* lskip  = (const float*)d_in[11];

  char* wsb = (char*)d_ws;
  float*  x     = (float*) (wsb + 0);           // 12,582,912 B
  ushort* h     = (ushort*)(wsb + 12582912);    //  6,291,456
  ushort* relb  = (ushort*)(wsb + 18874368);    //     98,304
  ushort* posb  = (ushort*)(wsb + 18972672);    //    196,608 (64 rows x 1536 bf16)
  ushort* vg    = (ushort*)(wsb + 19169280);    // 37,748,736
  ushort* qk    = (ushort*)(wsb + 56918016);    // 12,582,912
  ushort* cpT   = (ushort*)(wsb + 69500928);    //  6,291,456 (bf16 [96][64][512])
  ushort* cqT   = (ushort*)(wsb + 75792384);    //  6,291,456
  ushort* ctx   = (ushort*)(wsb + 82083840);    // 18,874,368
  ushort* vt    = (ushort*)(wsb + 100958208);   // 18,874,368
  ushort* ctxln = vt;                           // alias: disjoint live ranges
  ushort* wvqk  = (ushort*)(wsb + 119832576);   // [Wv;Wqk;Wo] bf16 contiguous: 12,976,128
  ushort* wqkb  = wvqk + (size_t)NW0;
  ushort* wob   = wvqk + (size_t)(NW0 + NW1);   // ends ~132.8 MB

  embed_ln_kernel<<<S*B, 256, 0, stream>>>(ids, wemb, x);
  rel_ln_kernel<<<63, 256, 0, stream>>>(rele, rlw, rlb, relb);

  for(int l=0; l<NL; l++){
    const float* Wv_l  = Wv  + (size_t)l * NW0;
    const float* Wqk_l = Wqk + (size_t)l * NW1;
    const float* bqk_l = bqk + (size_t)l * (2*H);
    const float* Wo_l  = Wo  + (size_t)l * NW2;
    const float* ls_l  = lskip + (size_t)l * II;

    f2b3_kernel<<<(NW0+NW1+NW2)/1024, 256, 0, stream>>>(Wv_l, Wqk_l, Wo_l, wvqk);

    ln_x_kernel<<<S*B, 256, 0, stream>>>(x, h);
    gemm_vgqk<<<dim3((2*II+2*H)/128, (S*B)/128), 256, 0, stream>>>(h, wvqk, bqk_l, vg, qk);
    gemm_nt64<<<dim3((2*H)/64, 1), 256, 0, stream>>>(relb, wqkb, bqk_l, posb, 63, 2*H, H);
    cpq_mfma2_kernel<<<dim3(S/128, B*NH, 2), 256, 0, stream>>>(qk, posb, cpT, cqT);
    vt_kernel<<<dim3(S/32, NH, B), 256, 0, stream>>>(vg, vt);
    attn_kernel<<<dim3(B*NH, S/32), 256, 0, stream>>>(qk, vt, cpT, cqT, pidx, ctx);
    glu_ln_kernel<<<S*B, 256, 0, stream>>>(ctx, vg, ls_l, ctxln);
    gemm128<2><<<dim3(H/128, (S*B)/128), 256, 0, stream>>>(ctxln, wob, nullptr, x, S*B, H, II);
  }
  copy_kernel<<<(S*B*H)/1024, 256, 0, stream>>>(x, (float*)d_out);
}

// Round 7
// 1258.336 us; speedup vs baseline: 1.1692x; 1.0638x over previous
//
#include <hip/hip_runtime.h>
#include <hip/hip_bf16.h>
#include <math.h>

#define S 512
#define B 8
#define H 768
#define NH 12
#define DH 64
#define DV 192
#define II 2304
#define NL 4
#define SCALE 0.07216878364870322f
#define EPS 1e-7f

#define NW0 (2*II*H)   // Wv elems  3,538,944
#define NW1 (2*H*H)    // Wqk elems 1,179,648
#define NW2 (H*II)     // Wo elems  1,769,472

typedef __attribute__((ext_vector_type(8))) short short8;
typedef __attribute__((ext_vector_type(4))) float f32x4;

__device__ __forceinline__ float b2f(ushort u){
  union { float f; unsigned int u; } v; v.u = ((unsigned int)u) << 16; return v.f;
}
__device__ __forceinline__ ushort f2b(float f){
  union { float f; unsigned int u; } v; v.f = f;
  unsigned int u = v.u;
  return (ushort)((u + 0x7fffu + ((u >> 16) & 1u)) >> 16);
}
__device__ __forceinline__ float gelu_f(float x){
  return 0.5f * x * (1.0f + erff(x * 0.70710678118654752f));
}
// async global(16B/lane) -> LDS (wave-uniform base + lane*16)
__device__ __forceinline__ void async_copy16(const ushort* g, ushort* l){
  __builtin_amdgcn_global_load_lds(
      (const __attribute__((address_space(1))) void*)g,
      (__attribute__((address_space(3))) void*)l, 16, 0, 0);
}

// ---- block-wide sum of two floats across 256 threads (4 waves) ----
__device__ __forceinline__ void block_sum2(float& s, float& s2, float* red, int t){
  #pragma unroll
  for(int off=32; off>=1; off>>=1){ s += __shfl_xor(s, off); s2 += __shfl_xor(s2, off); }
  int w = t >> 6;
  if((t & 63) == 0){ red[w] = s; red[4 + w] = s2; }
  __syncthreads();
  s  = red[0] + red[1] + red[2] + red[3];
  s2 = red[4] + red[5] + red[6] + red[7];
}

// ---- fused f32->bf16 convert of Wv|Wqk|Wo into one contiguous bf16 buffer ----
__global__ __launch_bounds__(256)
void f2b3_kernel(const float* __restrict__ in0, const float* __restrict__ in1,
                 const float* __restrict__ in2, ushort* __restrict__ out){
  int i = (blockIdx.x * 256 + threadIdx.x) * 4;
  const float* src; int off;
  if(i < NW0){ src = in0; off = i; }
  else if(i < NW0+NW1){ src = in1; off = i - NW0; }
  else { src = in2; off = i - NW0 - NW1; }
  float4 v = *(const float4*)(src + off);
  __attribute__((aligned(8))) ushort tmp[4] = { f2b(v.x), f2b(v.y), f2b(v.z), f2b(v.w) };
  *(uint2*)(out + i) = *(const uint2*)tmp;
}

// ---- x = LN(word_emb[ids])  (f32 in, f32 out) ----
__global__ __launch_bounds__(256)
void embed_ln_kernel(const int* __restrict__ ids, const float* __restrict__ wemb,
                     float* __restrict__ x)
{
  __shared__ float red[8];
  const int sb = blockIdx.x, t = threadIdx.x;
  const float* row = wemb + (size_t)ids[sb] * H;
  float v0 = row[t], v1 = row[t+256], v2 = row[t+512];
  float s = v0+v1+v2, s2 = v0*v0+v1*v1+v2*v2;
  block_sum2(s, s2, red, t);
  float mean = s * (1.0f/H);
  float rstd = rsqrtf(s2*(1.0f/H) - mean*mean + EPS);
  float* xo = x + (size_t)sb * H;
  xo[t]     = (v0-mean)*rstd;
  xo[t+256] = (v1-mean)*rstd;
  xo[t+512] = (v2-mean)*rstd;
}

// ---- relb = LN(rel_emb)*w + b  (f32 in, bf16 out) ----
__global__ __launch_bounds__(256)
void rel_ln_kernel(const float* __restrict__ rel_emb, const float* __restrict__ w,
                   const float* __restrict__ bia, ushort* __restrict__ outb)
{
  __shared__ float red[8];
  const int j = blockIdx.x, t = threadIdx.x;
  const float* row = rel_emb + (size_t)j * H;
  float v0=row[t], v1=row[t+256], v2=row[t+512];
  float s=v0+v1+v2, s2=v0*v0+v1*v1+v2*v2;
  block_sum2(s,s2,red,t);
  float mean = s*(1.0f/H);
  float rstd = rsqrtf(s2*(1.0f/H)-mean*mean+EPS);
  ushort* o = outb + (size_t)j*H;
  o[t]     = f2b((v0-mean)*rstd * w[t]     + bia[t]);
  o[t+256] = f2b((v1-mean)*rstd * w[t+256] + bia[t+256]);
  o[t+512] = f2b((v2-mean)*rstd * w[t+512] + bia[t+512]);
}

// ---- h = LN(x)  (bf16 out) ----
__global__ __launch_bounds__(256)
void ln_x_kernel(const float* __restrict__ x, ushort* __restrict__ h)
{
  __shared__ float red[8];
  const int sb = blockIdx.x, t = threadIdx.x;
  const float* row = x + (size_t)sb * H;
  float v0 = row[t], v1 = row[t+256], v2 = row[t+512];
  float s = v0+v1+v2, s2 = v0*v0+v1*v1+v2*v2;
  block_sum2(s, s2, red, t);
  float mean = s * (1.0f/H);
  float rstd = rsqrtf(s2*(1.0f/H) - mean*mean + EPS);
  ushort* o = h + (size_t)sb * H;
  o[t]     = f2b((v0-mean)*rstd);
  o[t+256] = f2b((v1-mean)*rstd);
  o[t+512] = f2b((v2-mean)*rstd);
}

// ---- small GEMM (64x64 tile): pos = relb @ Wqk^T + bqk (M=63) ----
__global__ __launch_bounds__(256)
void gemm_nt64(const ushort* __restrict__ A, const ushort* __restrict__ Bw,
               const float* __restrict__ bias, ushort* __restrict__ Cout,
               int M, int N, int K)
{
  __shared__ ushort As[64][40];
  __shared__ ushort Bs[64][40];
  const int n0 = blockIdx.x * 64, m0 = blockIdx.y * 64;
  const int t = threadIdx.x;
  const int lrow = t >> 2, lk = (t & 3) * 8;
  const int lane = t & 63, w = t >> 6, lr = lane & 15, lq = lane >> 4;
  const int wr = (w >> 1) * 32, wc = (w & 1) * 32;
  f32x4 z = {0.f,0.f,0.f,0.f};
  f32x4 acc[2][2] = {{z,z},{z,z}};
  const int arow = m0 + lrow;
  const ushort* aptr = A  + (size_t)arow * K + lk;
  const ushort* bptr = Bw + (size_t)(n0 + lrow) * K + lk;
  for(int k0 = 0; k0 < K; k0 += 32){
    short8 av = {0,0,0,0,0,0,0,0};
    if(arow < M) av = *(const short8*)(aptr + k0);
    short8 bv = *(const short8*)(bptr + k0);
    __syncthreads();
    *(short8*)&As[lrow][lk] = av;
    *(short8*)&Bs[lrow][lk] = bv;
    __syncthreads();
    short8 a0 = *(const short8*)&As[wr + lr][lq * 8];
    short8 a1 = *(const short8*)&As[wr + 16 + lr][lq * 8];
    short8 b0 = *(const short8*)&Bs[wc + lr][lq * 8];
    short8 b1 = *(const short8*)&Bs[wc + 16 + lr][lq * 8];
    acc[0][0] = __builtin_amdgcn_mfma_f32_16x16x32_bf16(a0, b0, acc[0][0], 0,0,0);
    acc[0][1] = __builtin_amdgcn_mfma_f32_16x16x32_bf16(a0, b1, acc[0][1], 0,0,0);
    acc[1][0] = __builtin_amdgcn_mfma_f32_16x16x32_bf16(a1, b0, acc[1][0], 0,0,0);
    acc[1][1] = __builtin_amdgcn_mfma_f32_16x16x32_bf16(a1, b1, acc[1][1], 0,0,0);
  }
  #pragma unroll
  for(int i=0;i<2;i++){
    #pragma unroll
    for(int j=0;j<2;j++){
      #pragma unroll
      for(int r=0;r<4;r++){
        int m = m0 + wr + i*16 + lq*4 + r;
        int n = n0 + wc + j*16 + lr;
        if(m >= M) continue;
        float v = acc[i][j][r];
        if(bias) v += bias[n];
        Cout[(size_t)m*N + n] = f2b(v);
      }
    }
  }
}

// ---- main GEMM: 128x128 tile, BK=64 (two 32-col LDS slabs) ----
// OUT_MODE: 0 = f32 store, 1 = bf16 store, 2 = f32 accumulate (+=)
template<int OUT_MODE>
__global__ __launch_bounds__(256)
void gemm128(const ushort* __restrict__ A, const ushort* __restrict__ Bw,
             const float* __restrict__ bias, void* __restrict__ Cout,
             int M, int N, int K)
{
  __shared__ ushort As[2][128*32];
  __shared__ ushort Bs[2][128*32];
  const int t = threadIdx.x, w = t>>6, lane = t&63, lr = lane&15, lq = lane>>4;
  const int m0 = blockIdx.y*128, n0 = blockIdx.x*128;
  const int wr = (w>>1)*64, wc = (w&1)*64;
  const int srow = (w*2)*16 + (lane>>2);
  const int sk = (lane&3)*8;
  const ushort* aG = A  + (size_t)(m0+srow)*K + sk;
  const ushort* bG = Bw + (size_t)(n0+srow)*K + sk;
  f32x4 z = {0.f,0.f,0.f,0.f};
  f32x4 acc[4][4] = {{z,z,z,z},{z,z,z,z},{z,z,z,z},{z,z,z,z}};
  for(int k0 = 0; k0 < K; k0 += 64){
    __syncthreads();
    #pragma unroll
    for(int s=0;s<2;s++){
      async_copy16(aG + k0 + s*32,                 As[s] + (w*2)*512);
      async_copy16(aG + k0 + s*32 + (size_t)16*K,  As[s] + (w*2+1)*512);
      async_copy16(bG + k0 + s*32,                 Bs[s] + (w*2)*512);
      async_copy16(bG + k0 + s*32 + (size_t)16*K,  Bs[s] + (w*2+1)*512);
    }
    __syncthreads();
    #pragma unroll
    for(int s=0;s<2;s++){
      short8 af[4], bf[4];
      #pragma unroll
      for(int i=0;i<4;i++) af[i] = *(const short8*)&As[s][(wr + i*16 + lr)*32 + lq*8];
      #pragma unroll
      for(int j=0;j<4;j++) bf[j] = *(const short8*)&Bs[s][(wc + j*16 + lr)*32 + lq*8];
      #pragma unroll
      for(int i=0;i<4;i++)
        #pragma unroll
        for(int j=0;j<4;j++)
          acc[i][j] = __builtin_amdgcn_mfma_f32_16x16x32_bf16(af[i], bf[j], acc[i][j], 0,0,0);
    }
  }
  #pragma unroll
  for(int i=0;i<4;i++){
    #pragma unroll
    for(int j=0;j<4;j++){
      #pragma unroll
      for(int r=0;r<4;r++){
        int m = m0 + wr + i*16 + lq*4 + r;
        int n = n0 + wc + j*16 + lr;
        float v = acc[i][j][r];
        if(bias) v += bias[n];
        if(OUT_MODE == 0)      ((float*) Cout)[(size_t)m*N + n] = v;
        else if(OUT_MODE == 1) ((ushort*)Cout)[(size_t)m*N + n] = f2b(v);
        else                   ((float*) Cout)[(size_t)m*N + n] += v;
      }
    }
  }
}

// ---- fused vg+qk GEMM (BK=64): Ww = [Wv(4608) ; Wqk(1536)] rows x 768 ----
__global__ __launch_bounds__(256)
void gemm_vgqk(const ushort* __restrict__ A, const ushort* __restrict__ Ww,
               const float* __restrict__ bqk, ushort* __restrict__ vg,
               ushort* __restrict__ qk)
{
  const int K = H;
  __shared__ ushort As[2][128*32];
  __shared__ ushort Bs[2][128*32];
  const int t = threadIdx.x, w = t>>6, lane = t&63, lr = lane&15, lq = lane>>4;
  const int m0 = blockIdx.y*128, n0 = blockIdx.x*128;
  const int wr = (w>>1)*64, wc = (w&1)*64;
  const int srow = (w*2)*16 + (lane>>2);
  const int sk = (lane&3)*8;
  const ushort* aG = A  + (size_t)(m0+srow)*K + sk;
  const ushort* bG = Ww + (size_t)(n0+srow)*K + sk;
  f32x4 z = {0.f,0.f,0.f,0.f};
  f32x4 acc[4][4] = {{z,z,z,z},{z,z,z,z},{z,z,z,z},{z,z,z,z}};
  for(int k0 = 0; k0 < K; k0 += 64){
    __syncthreads();
    #pragma unroll
    for(int s=0;s<2;s++){
      async_copy16(aG + k0 + s*32,                 As[s] + (w*2)*512);
      async_copy16(aG + k0 + s*32 + (size_t)16*K,  As[s] + (w*2+1)*512);
      async_copy16(bG + k0 + s*32,                 Bs[s] + (w*2)*512);
      async_copy16(bG + k0 + s*32 + (size_t)16*K,  Bs[s] + (w*2+1)*512);
    }
    __syncthreads();
    #pragma unroll
    for(int s=0;s<2;s++){
      short8 af[4], bf[4];
      #pragma unroll
      for(int i=0;i<4;i++) af[i] = *(const short8*)&As[s][(wr + i*16 + lr)*32 + lq*8];
      #pragma unroll
      for(int j=0;j<4;j++) bf[j] = *(const short8*)&Bs[s][(wc + j*16 + lr)*32 + lq*8];
      #pragma unroll
      for(int i=0;i<4;i++)
        #pragma unroll
        for(int j=0;j<4;j++)
          acc[i][j] = __builtin_amdgcn_mfma_f32_16x16x32_bf16(af[i], bf[j], acc[i][j], 0,0,0);
    }
  }
  const bool is_qk = (n0 >= 2*II);
  #pragma unroll
  for(int i=0;i<4;i++){
    #pragma unroll
    for(int j=0;j<4;j++){
      #pragma unroll
      for(int r=0;r<4;r++){
        int m = m0 + wr + i*16 + lq*4 + r;
        int n = n0 + wc + j*16 + lr;
        float v = acc[i][j][r];
        if(is_qk){
          int nq = n - 2*II;
          qk[(size_t)m*(2*H) + nq] = f2b(v + bqk[nq]);
        } else {
          vg[(size_t)m*(2*II) + n] = f2b(v);
        }
      }
    }
  }
}

// ---- merged: Vt transpose (blocks [0,1536)) + cp/cq MFMA (blocks [1536,2304)) ----
__global__ __launch_bounds__(256)
void vtcpq_kernel(const ushort* __restrict__ vg, ushort* __restrict__ vt,
                  const ushort* __restrict__ qk, const ushort* __restrict__ posb,
                  ushort* __restrict__ cpT, ushort* __restrict__ cqT)
{
  const int id = blockIdx.x;
  const int t = threadIdx.x;
  __shared__ ushort tile[32][200];
  if(id < 1536){
    const int st = id & 15;
    const int hh = (id >> 4) % 12;
    const int b  = id / 192;
    {
      int sl = t >> 3, v0 = (t & 7) * 24;
      const ushort* src = vg + ((size_t)((st*32 + sl)*B + b))*(2*II) + hh*DV + v0;
      *(short8*)&tile[sl][v0]      = *(const short8*)(src);
      *(short8*)&tile[sl][v0 + 8]  = *(const short8*)(src + 8);
      *(short8*)&tile[sl][v0 + 16] = *(const short8*)(src + 16);
    }
    __syncthreads();
    if(t < DV){
      __attribute__((aligned(16))) ushort tmp[32];
      #pragma unroll
      for(int s2=0;s2<32;s2++) tmp[s2] = tile[s2][t];
      ushort* dst = vt + (((size_t)(b*NH + hh))*DV + t)*S + st*32;
      #pragma unroll
      for(int c=0;c<32;c+=8) *(short8*)(dst + c) = *(const short8*)&tmp[c];
    }
  } else {
    const int jid = id - 1536;
    const int kc = jid & 3;
    const int bh = (jid >> 2) % 96;
    const int which = jid / 384;
    const int bb = bh / NH, h = bh - bb*NH;
    const int w = t>>6, lane = t&63, lr = lane&15, lq = lane>>4;
    const ushort* ab = posb + (size_t)(w*16 + lr)*1536 + (which ? 0 : 768) + h*64;
    short8 a0 = *(const short8*)(ab + lq*8);
    short8 a1 = *(const short8*)(ab + 32 + lq*8);
    f32x4 z = {0.f,0.f,0.f,0.f};
    f32x4 acc[8] = {z,z,z,z,z,z,z,z};
    #pragma unroll
    for(int nt=0; nt<8; nt++){
      const int k = kc*128 + nt*16 + lr;
      const ushort* bp = qk + ((size_t)k*B + bb)*1536 + (which ? 768 : 0) + h*64;
      short8 b0 = *(const short8*)(bp + lq*8);
      short8 b1 = *(const short8*)(bp + 32 + lq*8);
      acc[nt] = __builtin_amdgcn_mfma_f32_16x16x32_bf16(a0, b0, acc[nt], 0,0,0);
      acc[nt] = __builtin_amdgcn_mfma_f32_16x16x32_bf16(a1, b1, acc[nt], 0,0,0);
    }
    ushort* outp = which ? cqT : cpT;
    #pragma unroll
    for(int nt=0; nt<8; nt++){
      #pragma unroll
      for(int r=0;r<4;r++){
        int j = w*16 + lq*4 + r;
        int k = kc*128 + nt*16 + lr;
        outp[((size_t)bh*64 + j)*512 + k] = f2b(acc[nt][r]);
      }
    }
  }
}

// ---- fused attention, 32 q-rows per block; grid (bh=96, qt=16) ----
__global__ __launch_bounds__(256)
void attn_kernel(const ushort* __restrict__ qk, const ushort* __restrict__ vt,
                 const ushort* __restrict__ cpT, const ushort* __restrict__ cqT,
                 const int* __restrict__ pidx, ushort* __restrict__ ctx)
{
  const int bh = blockIdx.x, qt = blockIdx.y;
  const int b = bh / NH, hh = bh - b*NH;
  __shared__ ushort Qs[32][72];
  __shared__ ushort Ps[32][520];
  __shared__ float cps[32][65];
  __shared__ float redm[4][32];
  __shared__ float reds[4][32];
  __shared__ float rowinv[32];
  const int t = threadIdx.x, w = t>>6, lane = t&63, lr = lane&15, lq = lane>>4;

  for(int i=t; i<512; i+=256){
    int r = i >> 4, d0 = (i & 15) * 4;
    const ushort* src = qk + ((size_t)((qt*32 + r)*B + b))*1536 + hh*DH + d0;
    *(uint2*)&Qs[r][d0] = *(const uint2*)src;
  }
  for(int i=t; i<32*64; i+=256){
    int j = i >> 5, r = i & 31;
    cps[r][j] = b2f(cpT[((size_t)bh*64 + j)*512 + qt*32 + r]);
  }
  __syncthreads();

  short8 a00 = *(const short8*)&Qs[lr][lq*8];
  short8 a01 = *(const short8*)&Qs[lr][32 + lq*8];
  short8 a10 = *(const short8*)&Qs[16 + lr][lq*8];
  short8 a11 = *(const short8*)&Qs[16 + lr][32 + lq*8];

  float sc[8][8];
  const int kbase = w * 128;
  const ushort* cqbase = cqT + (size_t)bh*64*512;
  f32x4 z4 = {0.f,0.f,0.f,0.f};
  #pragma unroll
  for(int tile=0; tile<8; tile++){
    const int k0 = kbase + tile*16;
    const ushort* kp = qk + ((size_t)((k0 + lr)*B + b))*1536 + H + hh*DH + lq*8;
    short8 b0 = *(const short8*)kp;
    short8 b1 = *(const short8*)(kp + 32);
    f32x4 acc[2] = {z4, z4};
    acc[0] = __builtin_amdgcn_mfma_f32_16x16x32_bf16(a00, b0, acc[0], 0,0,0);
    acc[0] = __builtin_amdgcn_mfma_f32_16x16x32_bf16(a01, b1, acc[0], 0,0,0);
    acc[1] = __builtin_amdgcn_mfma_f32_16x16x32_bf16(a10, b0, acc[1], 0,0,0);
    acc[1] = __builtin_amdgcn_mfma_f32_16x16x32_bf16(a11, b1, acc[1], 0,0,0);
    const int kcol = k0 + lr;
    #pragma unroll
    for(int qs=0;qs<2;qs++){
      #pragma unroll
      for(int r=0;r<4;r++){
        int ql = qs*16 + lq*4 + r;
        int pi = pidx[(qt*32+ql)*S + kcol];
        sc[tile][qs*4+r] = (acc[qs][r] + cps[ql][pi]
                       + b2f(cqbase[(size_t)pi*512 + kcol])) * SCALE;
      }
    }
  }

  float gm[8];
  #pragma unroll
  for(int j=0;j<8;j++){
    float m = sc[0][j];
    #pragma unroll
    for(int tile=1;tile<8;tile++) m = fmaxf(m, sc[tile][j]);
    #pragma unroll
    for(int off=1; off<16; off<<=1) m = fmaxf(m, __shfl_xor(m, off));
    if(lr==0) redm[w][(j>>2)*16 + lq*4 + (j&3)] = m;
  }
  __syncthreads();
  #pragma unroll
  for(int j=0;j<8;j++){
    int ql = (j>>2)*16 + lq*4 + (j&3);
    gm[j] = fmaxf(fmaxf(redm[0][ql],redm[1][ql]),fmaxf(redm[2][ql],redm[3][ql]));
  }
  #pragma unroll
  for(int j=0;j<8;j++){
    float s = 0.f;
    #pragma unroll
    for(int tile=0;tile<8;tile++){ float e = __expf(sc[tile][j]-gm[j]); sc[tile][j]=e; s+=e; }
    #pragma unroll
    for(int off=1; off<16; off<<=1) s += __shfl_xor(s, off);
    if(lr==0) reds[w][(j>>2)*16 + lq*4 + (j&3)] = s;
  }
  __syncthreads();
  #pragma unroll
  for(int j=0;j<8;j++){
    int ql = (j>>2)*16 + lq*4 + (j&3);
    float g = reds[0][ql]+reds[1][ql]+reds[2][ql]+reds[3][ql];
    if(w==0 && lr==0) rowinv[ql] = 1.0f/g;
  }
  #pragma unroll
  for(int tile=0;tile<8;tile++){
    #pragma unroll
    for(int j=0;j<8;j++){
      int ql = (j>>2)*16 + lq*4 + (j&3);
      Ps[ql][kbase + tile*16 + lr] = f2b(sc[tile][j]);
    }
  }
  __syncthreads();

  f32x4 acc2[2][3] = {{z4,z4,z4},{z4,z4,z4}};
  const ushort* vbase = vt + ((size_t)bh)*DV*S;
  #pragma unroll 4
  for(int kk=0; kk<S; kk+=32){
    short8 p0 = *(const short8*)&Ps[lr][kk + lq*8];
    short8 p1 = *(const short8*)&Ps[16 + lr][kk + lq*8];
    #pragma unroll
    for(int ti=0; ti<3; ti++){
      const int v0 = (w*3 + ti)*16;
      short8 bv = *(const short8*)(vbase + (size_t)(v0 + lr)*S + kk + lq*8);
      acc2[0][ti] = __builtin_amdgcn_mfma_f32_16x16x32_bf16(p0, bv, acc2[0][ti], 0,0,0);
      acc2[1][ti] = __builtin_amdgcn_mfma_f32_16x16x32_bf16(p1, bv, acc2[1][ti], 0,0,0);
    }
  }
  #pragma unroll
  for(int qs=0;qs<2;qs++){
    #pragma unroll
    for(int ti=0; ti<3; ti++){
      const int v0 = (w*3 + ti)*16;
      #pragma unroll
      for(int r=0;r<4;r++){
        int ql = qs*16 + lq*4 + r;
        float val = acc2[qs][ti][r] * rowinv[ql];
        ctx[((size_t)((qt*32+ql)*B + b))*II + hh*DV + v0 + lr] = f2b(val);
      }
    }
  }
}

// ---- ctx2 = LN( (ctx + sigmoid(lskip)*gelu(value)) * gelu(gate) )  (bf16) ----
__global__ __launch_bounds__(256)
void glu_ln_kernel(const ushort* __restrict__ ctx, const ushort* __restrict__ vg,
                   const float* __restrict__ ls, ushort* __restrict__ outb)
{
  __shared__ float red[8];
  const int sb = blockIdx.x, t = threadIdx.x;
  const ushort* crow = ctx + (size_t)sb*II;
  const ushort* vrow = vg + (size_t)sb*2*II;
  float c[9]; float s=0.f, s2=0.f;
  #pragma unroll
  for(int i=0;i<9;i++){
    int idx = t + i*256;
    float cv  = b2f(crow[idx]);
    float val = b2f(vrow[idx]);
    float gt  = b2f(vrow[II + idx]);
    float sk  = 1.0f/(1.0f + __expf(-ls[idx]));
    cv = (cv + sk*gelu_f(val)) * gelu_f(gt);
    c[i]=cv; s+=cv; s2+=cv*cv;
  }
  block_sum2(s,s2,red,t);
  float mean = s*(1.0f/II);
  float rstd = rsqrtf(s2*(1.0f/II)-mean*mean+EPS);
  ushort* o = outb + (size_t)sb*II;
  #pragma unroll
  for(int i=0;i<9;i++) o[t+i*256] = f2b((c[i]-mean)*rstd);
}

// ---- final copy x(f32) -> out(f32) ----
__global__ __launch_bounds__(256)
void copy_kernel(const float* __restrict__ x, float* __restrict__ out){
  int i = (blockIdx.x*256 + threadIdx.x)*4;
  *(float4*)(out + i) = *(const float4*)(x + i);
}

extern "C" void kernel_launch(void* const* d_in, const int* in_sizes, int n_in,
                              void* d_out, int out_size, void* d_ws, size_t ws_size,
                              hipStream_t stream)
{
  (void)in_sizes; (void)n_in; (void)out_size; (void)ws_size;
  const int* ids      = (const int*)d_in[0];
  const int* pidx     = (const int*)d_in[2];
  const float* wemb   = (const float*)d_in[3];
  const float* rele   = (const float*)d_in[4];
  const float* rlw    = (const float*)d_in[5];
  const float* rlb    = (const float*)d_in[6];
  const float* Wv     = (const float*)d_in[7];
  const float* Wqk    = (const float*)d_in[8];
  const float* bqk    = (const float*)d_in[9];
  const float* Wo     = (const float*)d_in[10];
  const float* lskip  = (const float*)d_in[11];

  char* wsb = (char*)d_ws;
  float*  x     = (float*) (wsb + 0);           // 12,582,912 B
  ushort* h     = (ushort*)(wsb + 12582912);    //  6,291,456
  ushort* relb  = (ushort*)(wsb + 18874368);    //     98,304
  ushort* posb  = (ushort*)(wsb + 18972672);    //    196,608 (64 rows x 1536 bf16)
  ushort* vg    = (ushort*)(wsb + 19169280);    // 37,748,736
  ushort* qk    = (ushort*)(wsb + 56918016);    // 12,582,912
  ushort* cpT   = (ushort*)(wsb + 69500928);    //  6,291,456 (bf16 [96][64][512])
  ushort* cqT   = (ushort*)(wsb + 75792384);    //  6,291,456
  ushort* ctx   = (ushort*)(wsb + 82083840);    // 18,874,368
  ushort* vt    = (ushort*)(wsb + 100958208);   // 18,874,368
  ushort* ctxln = vt;                           // alias: disjoint live ranges
  ushort* wvqk  = (ushort*)(wsb + 119832576);   // [Wv;Wqk;Wo] bf16 contiguous: 12,976,128
  ushort* wqkb  = wvqk + (size_t)NW0;
  ushort* wob   = wvqk + (size_t)(NW0 + NW1);   // ends ~132.8 MB

  embed_ln_kernel<<<S*B, 256, 0, stream>>>(ids, wemb, x);
  rel_ln_kernel<<<63, 256, 0, stream>>>(rele, rlw, rlb, relb);

  for(int l=0; l<NL; l++){
    const float* Wv_l  = Wv  + (size_t)l * NW0;
    const float* Wqk_l = Wqk + (size_t)l * NW1;
    const float* bqk_l = bqk + (size_t)l * (2*H);
    const float* Wo_l  = Wo  + (size_t)l * NW2;
    const float* ls_l  = lskip + (size_t)l * II;

    f2b3_kernel<<<(NW0+NW1+NW2)/1024, 256, 0, stream>>>(Wv_l, Wqk_l, Wo_l, wvqk);
    ln_x_kernel<<<S*B, 256, 0, stream>>>(x, h);
    gemm_nt64<<<dim3((2*H)/64, 1), 256, 0, stream>>>(relb, wqkb, bqk_l, posb, 63, 2*H, H);
    gemm_vgqk<<<dim3((2*II+2*H)/128, (S*B)/128), 256, 0, stream>>>(h, wvqk, bqk_l, vg, qk);
    vtcpq_kernel<<<2304, 256, 0, stream>>>(vg, vt, qk, posb, cpT, cqT);
    attn_kernel<<<dim3(B*NH, S/32), 256, 0, stream>>>(qk, vt, cpT, cqT, pidx, ctx);
    glu_ln_kernel<<<S*B, 256, 0, stream>>>(ctx, vg, ls_l, ctxln);
    gemm128<2><<<dim3(H/128, (S*B)/128), 256, 0, stream>>>(ctxln, wob, nullptr, x, S*B, H, II);
  }
  copy_kernel<<<(S*B*H)/1024, 256, 0, stream>>>(x, (float*)d_out);
}